// Round 1
// baseline (294.246 us; speedup 1.0000x reference)
//
#include <hip/hip_runtime.h>

// Problem constants (MovementEmbeddingModule): bs=4, d=16, K=10, C=3, h=w=128
#define BS 4
#define DD 16
#define KK 10
#define CC 3
#define HH 128
#define WW 128
// out: (4, 60, 16, 128, 128) f32; out[b][k*6+c][d][y][x]

__global__ __launch_bounds__(256) void movement_embed_kernel(
    const float* __restrict__ kp_app,   // (4,1,10,2)
    const float* __restrict__ kp_vid,   // (4,16,10,2)
    const float* __restrict__ img,      // (4,3,128,128)  (appearance_frame[:, :, 0])
    float* __restrict__ out)
{
    // 16 blocks per (b,d,k) tile; each block: 256 threads over 4096 float4 slots / 16
    const unsigned bi  = blockIdx.x;
    const unsigned sub = bi & 15u;
    const unsigned bdk = bi >> 4;
    const unsigned k   = bdk % KK;
    const unsigned t2  = bdk / KK;
    const unsigned d   = t2 % DD;
    const unsigned b   = t2 / DD;

    const unsigned p  = sub * 256u + threadIdx.x;  // 0..4095
    const unsigned xg = p & 31u;                   // float4 column (32 per row)
    const unsigned y  = p >> 5;                    // row 0..127

    // Wave-uniform keypoint loads (b,d,k come from blockIdx -> SGPR, s_load path)
    const float kvx  = kp_vid[((b*DD + d)*KK + k)*2 + 0];
    const float kvy  = kp_vid[((b*DD + d)*KK + k)*2 + 1];
    const float kv0x = kp_vid[((b*DD + 0)*KK + k)*2 + 0];
    const float kv0y = kp_vid[((b*DD + 0)*KK + k)*2 + 1];
    const float kax  = kp_app[(b*KK + k)*2 + 0];
    const float kay  = kp_app[(b*KK + k)*2 + 1];

    const float diffx = kvx - kv0x;           // diff = kp_video - kp_video[:,0:1]
    const float diffy = kvy - kv0y;
    const float mx = diffx + kax;             // kp_mean (heatmap center, current frame)
    const float my = diffy + kay;
    const float vdx = -diffx;                 // kp_video_diff (diff-map consts + warp shift)
    const float vdy = -diffy;

    const float step = 2.0f / 127.0f;
    const float gy = (float)y * step - 1.0f;

    // y part of bilinear (constant across the row)
    const float yi  = (gy + vdy + 1.0f) * 63.5f;   // (coord+1)*(H-1)/2
    const float y0f = floorf(yi);
    const float fy  = yi - y0f;
    const int   y0  = (int)y0f;
    const int   y1  = y0 + 1;
    const float wy0 = (1.0f - fy) * ((y0 >= 0 && y0 < HH) ? 1.0f : 0.0f);
    const float wy1 = fy          * ((y1 >= 0 && y1 < HH) ? 1.0f : 0.0f);
    const int   y0c = min(max(y0, 0), HH - 1);
    const int   y1c = min(max(y1, 0), HH - 1);

    const float dy1 = gy - my;
    const float dy0 = gy - kay;
    const float dy1sq = dy1 * dy1;
    const float dy0sq = dy0 * dy0;

    const float* imgb = img + (size_t)b * CC * HH * WW;

    float hv[4];
    float dv[CC][4];

#pragma unroll
    for (int j = 0; j < 4; ++j) {
        const int   x  = (int)(xg * 4u) + j;
        const float gx = (float)x * step - 1.0f;

        // heatmap: exp(-0.5*r2/0.01) = exp(-50*r2); d-frame minus d0-frame (exact 0 at d=0)
        const float dx1 = gx - mx;
        const float dx0 = gx - kax;
        const float e1 = __expf(-50.0f * (dx1 * dx1 + dy1sq));
        const float e0 = __expf(-50.0f * (dx0 * dx0 + dy0sq));
        hv[j] = e1 - e0;

        // bilinear sample of img at grid + kp_video_diff (zeros padding, align_corners)
        const float xi  = (gx + vdx + 1.0f) * 63.5f;
        const float x0f = floorf(xi);
        const float fx  = xi - x0f;
        const int   x0  = (int)x0f;
        const int   x1  = x0 + 1;
        const float wx0 = (1.0f - fx) * ((x0 >= 0 && x0 < WW) ? 1.0f : 0.0f);
        const float wx1 = fx          * ((x1 >= 0 && x1 < WW) ? 1.0f : 0.0f);
        const int   x0c = min(max(x0, 0), WW - 1);
        const int   x1c = min(max(x1, 0), WW - 1);

        const float w00 = wx0 * wy0, w10 = wx1 * wy0;
        const float w01 = wx0 * wy1, w11 = wx1 * wy1;

#pragma unroll
        for (int c = 0; c < CC; ++c) {
            const float* pc = imgb + (size_t)c * HH * WW;
            const float* r0 = pc + (size_t)y0c * WW;
            const float* r1 = pc + (size_t)y1c * WW;
            dv[c][j] = w00 * r0[x0c] + w10 * r0[x1c]
                     + w01 * r1[x0c] + w11 * r1[x1c];
        }
    }

    // stores: out[b][k*6+c][d][y][x], channel stride = D*H*W
    const size_t chs  = (size_t)DD * HH * WW;  // 262144
    const size_t base = ((((size_t)b * (KK * 6) + k * 6) * DD + d) * HH + y) * WW + xg * 4u;

    *(float4*)(out + base)           = make_float4(hv[0], hv[1], hv[2], hv[3]);
    *(float4*)(out + base + chs)     = make_float4(vdx, vdx, vdx, vdx);
    *(float4*)(out + base + 2*chs)   = make_float4(vdy, vdy, vdy, vdy);
#pragma unroll
    for (int c = 0; c < CC; ++c) {
        *(float4*)(out + base + (size_t)(3 + c) * chs) =
            make_float4(dv[c][0], dv[c][1], dv[c][2], dv[c][3]);
    }
}

extern "C" void kernel_launch(void* const* d_in, const int* in_sizes, int n_in,
                              void* d_out, int out_size, void* d_ws, size_t ws_size,
                              hipStream_t stream) {
    const float* kp_app = (const float*)d_in[0];   // (4,1,10,2)
    const float* kp_vid = (const float*)d_in[1];   // (4,16,10,2)
    const float* img    = (const float*)d_in[2];   // (4,3,1,128,128)
    float* out = (float*)d_out;                    // (4,60,16,128,128)

    // 16 blocks per (b,d,k): 4*16*10*16 = 10240 blocks of 256 threads
    const int nblocks = BS * DD * KK * 16;
    movement_embed_kernel<<<nblocks, 256, 0, stream>>>(kp_app, kp_vid, img, out);
}

// Round 2
// 254.642 us; speedup vs baseline: 1.1555x; 1.1555x over previous
//
#include <hip/hip_runtime.h>

// MovementEmbeddingModule: bs=4, d=16, K=10, C=3, h=w=128
// out: (4, 60, 16, 128, 128) f32; out[b][k*6+c][d][y][x]
#define BS 4
#define DD 16
#define KK 10
#define CC 3
#define HH 128
#define WW 128

#define NROWS 9     // 8 output rows per block -> 9 source rows (ri0 0..7, ri1 1..8)
#define LROW 132    // 129 staged cols, padded to 132 (16B-multiple row stride)

__global__ __launch_bounds__(256) void movement_embed_kernel(
    const float* __restrict__ kp_app,   // (4,1,10,2)
    const float* __restrict__ kp_vid,   // (4,16,10,2)
    const float* __restrict__ img,      // (4,3,128,128)
    float* __restrict__ out)
{
    __shared__ __align__(16) float P[CC][NROWS][LROW];  // 14,256 B

    const unsigned bi  = blockIdx.x;
    const unsigned sub = bi & 15u;          // 16 row-tiles (8 rows each) per (b,d,k)
    const unsigned bdk = bi >> 4;
    const unsigned k   = bdk % KK;
    const unsigned t2  = bdk / KK;
    const unsigned d   = t2 % DD;
    const unsigned b   = t2 / DD;
    const int tid = (int)threadIdx.x;

    // wave-uniform keypoint math (SGPR path)
    const float kvx  = kp_vid[((b*DD + d)*KK + k)*2 + 0];
    const float kvy  = kp_vid[((b*DD + d)*KK + k)*2 + 1];
    const float kv0x = kp_vid[((b*DD + 0)*KK + k)*2 + 0];
    const float kv0y = kp_vid[((b*DD + 0)*KK + k)*2 + 1];
    const float kax  = kp_app[(b*KK + k)*2 + 0];
    const float kay  = kp_app[(b*KK + k)*2 + 1];

    const float diffx = kvx - kv0x;     // exactly 0 at d==0
    const float diffy = kvy - kv0y;
    const float mx = diffx + kax;       // heatmap center
    const float my = diffy + kay;
    const float vdx = -diffx;           // kp_video_diff (diff-map consts + warp shift)
    const float vdy = -diffy;

    // Uniform bilinear decomposition: sample coord = pixel + c (since step*63.5 == 1.0)
    const float cx = vdx * 63.5f;
    const float cy = vdy * 63.5f;
    const float fcx = floorf(cx);
    const float fcy = floorf(cy);
    const int icx = (int)fcx;
    const int icy = (int)fcy;
    const float wx1 = cx - fcx, wx0 = 1.0f - wx1;   // block-uniform weights
    const float wy1 = cy - fcy, wy0 = 1.0f - wy1;

    const int R0 = (int)(sub * 8u) + icy;           // first source row
    const float* imgb = img + (size_t)b * (CC*HH*WW);

    // ---- stage 3ch x 9 rows x 129 cols, zero-padded, into LDS ----
    // P[c][ri][tt] = img[c][R0+ri][icx+tt] or 0  (tt in [0,128])
    for (int idx = tid; idx < CC*NROWS*129; idx += 256) {
        const int tt    = idx % 129;
        const int rowix = idx / 129;        // 0..26
        const int ri = rowix % NROWS;
        const int c  = rowix / NROWS;
        const int r   = R0 + ri;
        const int col = icx + tt;
        float v = 0.0f;
        if ((unsigned)r < (unsigned)HH && (unsigned)col < (unsigned)WW)
            v = imgb[(c*HH + r)*WW + col];
        P[c][ri][tt] = v;
    }
    __syncthreads();

    // ---- compute ----
    const int xg = tid & 31;        // float4 column
    const int ly = tid >> 5;        // local row 0..7
    const int x4 = xg * 4;
    const int y  = (int)(sub * 8u) + ly;

    const float step = 2.0f / 127.0f;
    const float gy  = (float)y  * step - 1.0f;
    const float gx0 = (float)x4 * step - 1.0f;

    // heatmap: exp(-50*r^2(kp_mean)) - exp(-50*r^2(kp_app)); exact 0 at d==0
    const float dy1 = gy - my, dy0 = gy - kay;
    const float dy1sq = dy1 * dy1, dy0sq = dy0 * dy0;
    float hv[4];
#pragma unroll
    for (int j = 0; j < 4; ++j) {
        const float gx = gx0 + (float)j * step;
        const float dx1 = gx - mx, dx0 = gx - kax;
        hv[j] = __expf(-50.0f * (dx1 * dx1 + dy1sq))
              - __expf(-50.0f * (dx0 * dx0 + dy0sq));
    }

    // deformed: uniform-weight blend of shifted rows from LDS
    float4 dvc[CC];
#pragma unroll
    for (int c = 0; c < CC; ++c) {
        const float* row0 = &P[c][ly][x4];
        const float* row1 = &P[c][ly + 1][x4];
        const float4 A = *(const float4*)row0;
        const float  ea = row0[4];
        const float4 B = *(const float4*)row1;
        const float  eb = row1[4];
        const float h0x = wx0 * A.x + wx1 * A.y;
        const float h0y = wx0 * A.y + wx1 * A.z;
        const float h0z = wx0 * A.z + wx1 * A.w;
        const float h0w = wx0 * A.w + wx1 * ea;
        const float h1x = wx0 * B.x + wx1 * B.y;
        const float h1y = wx0 * B.y + wx1 * B.z;
        const float h1z = wx0 * B.z + wx1 * B.w;
        const float h1w = wx0 * B.w + wx1 * eb;
        dvc[c] = make_float4(wy0 * h0x + wy1 * h1x,
                             wy0 * h0y + wy1 * h1y,
                             wy0 * h0z + wy1 * h1z,
                             wy0 * h0w + wy1 * h1w);
    }

    // ---- stores: out[b][k*6+c][d][y][x] ----
    const size_t chs  = (size_t)DD * HH * WW;  // 262144
    const size_t base = ((((size_t)b * (KK * 6) + k * 6) * DD + d) * HH + y) * WW + (size_t)x4;

    *(float4*)(out + base)         = make_float4(hv[0], hv[1], hv[2], hv[3]);
    *(float4*)(out + base + chs)   = make_float4(vdx, vdx, vdx, vdx);
    *(float4*)(out + base + 2*chs) = make_float4(vdy, vdy, vdy, vdy);
#pragma unroll
    for (int c = 0; c < CC; ++c)
        *(float4*)(out + base + (size_t)(3 + c) * chs) = dvc[c];
}

extern "C" void kernel_launch(void* const* d_in, const int* in_sizes, int n_in,
                              void* d_out, int out_size, void* d_ws, size_t ws_size,
                              hipStream_t stream) {
    const float* kp_app = (const float*)d_in[0];   // (4,1,10,2)
    const float* kp_vid = (const float*)d_in[1];   // (4,16,10,2)
    const float* img    = (const float*)d_in[2];   // (4,3,1,128,128)
    float* out = (float*)d_out;                    // (4,60,16,128,128)

    const int nblocks = BS * DD * KK * 16;         // 10240
    movement_embed_kernel<<<nblocks, 256, 0, stream>>>(kp_app, kp_vid, img, out);
}

// Round 3
// 250.197 us; speedup vs baseline: 1.1761x; 1.0178x over previous
//
#include <hip/hip_runtime.h>

// MovementEmbeddingModule: bs=4, d=16, K=10, C=3, h=w=128
// out: (4, 60, 16, 128, 128) f32; out[b][k*6+c][d][y][x]
#define BS 4
#define DD 16
#define KK 10
#define CC 3
#define HH 128
#define WW 128

#define NROWS 9     // 8 output rows per block -> 9 source rows
#define LROW 132    // 129 staged cols, padded to 132 (16B-multiple row stride)

__global__ __launch_bounds__(256) void movement_embed_kernel(
    const float* __restrict__ kp_app,   // (4,1,10,2)
    const float* __restrict__ kp_vid,   // (4,16,10,2)
    const float* __restrict__ img,      // (4,3,128,128)
    float* __restrict__ out)
{
    __shared__ __align__(16) float P[CC][NROWS][LROW];  // 14,256 B

    const unsigned bi  = blockIdx.x;
    const unsigned sub = bi & 15u;          // 16 row-tiles (8 rows each) per (b,d,k)
    const unsigned bdk = bi >> 4;
    const unsigned k   = bdk % KK;
    const unsigned t2  = bdk / KK;
    const unsigned d   = t2 % DD;
    const unsigned b   = t2 / DD;
    const int tid  = (int)threadIdx.x;
    const int lane = tid & 63;
    const int wv   = tid >> 6;              // wave id 0..3

    // wave-uniform keypoint math (SGPR path)
    const float kvx  = kp_vid[((b*DD + d)*KK + k)*2 + 0];
    const float kvy  = kp_vid[((b*DD + d)*KK + k)*2 + 1];
    const float kv0x = kp_vid[((b*DD + 0)*KK + k)*2 + 0];
    const float kv0y = kp_vid[((b*DD + 0)*KK + k)*2 + 1];
    const float kax  = kp_app[(b*KK + k)*2 + 0];
    const float kay  = kp_app[(b*KK + k)*2 + 1];

    const float diffx = kvx - kv0x;     // exactly 0 at d==0
    const float diffy = kvy - kv0y;
    const float mx = diffx + kax;       // heatmap center
    const float my = diffy + kay;
    const float vdx = -diffx;           // kp_video_diff (diff-map consts + warp shift)
    const float vdy = -diffy;

    // Uniform bilinear decomposition: sample coord = pixel + c (step*(W-1)/2 == 1.0)
    const float cx = vdx * 63.5f;
    const float cy = vdy * 63.5f;
    const float fcx = floorf(cx);
    const float fcy = floorf(cy);
    const int icx = (int)fcx;
    const int icy = (int)fcy;
    const float wx1 = cx - fcx, wx0 = 1.0f - wx1;   // block-uniform weights
    const float wy1 = cy - fcy, wy0 = 1.0f - wy1;

    const int R0 = (int)(sub * 8u) + icy;           // first source row
    const float* imgb = img + (size_t)b * (CC*HH*WW);

    // ---- stage 3ch x 9 rows x 129 cols (zero-padded) into LDS ----
    // Fully unrolled (c,ri) tasks, striped over the 4 waves; clamped addrs +
    // cndmask zeroing (no divergent branches, no integer division).
#pragma unroll
    for (int c = 0; c < CC; ++c) {
        const float* pc = imgb + c * (HH * WW);
#pragma unroll
        for (int ri = 0; ri < NROWS; ++ri) {
            if (((c * NROWS + ri) & 3) == wv) {     // wave-uniform scalar predicate
                const int  r   = R0 + ri;
                const bool rok = (unsigned)r < (unsigned)HH;
                const float* rp = pc + (size_t)min(max(r, 0), HH - 1) * WW;

                const int c0 = icx + lane;
                const int c1 = c0 + 64;
                float v0 = rp[min(max(c0, 0), WW - 1)];
                float v1 = rp[min(max(c1, 0), WW - 1)];
                v0 = (rok && (unsigned)c0 < (unsigned)WW) ? v0 : 0.0f;
                v1 = (rok && (unsigned)c1 < (unsigned)WW) ? v1 : 0.0f;
                P[c][ri][lane]      = v0;
                P[c][ri][lane + 64] = v1;
                if (lane == 0) {                    // col 128 tail
                    const int c2 = icx + 128;
                    float v2 = rp[min(max(c2, 0), WW - 1)];
                    P[c][ri][128] = (rok && (unsigned)c2 < (unsigned)WW) ? v2 : 0.0f;
                }
            }
        }
    }
    __syncthreads();

    // ---- compute ----
    const int xg = tid & 31;        // float4 column
    const int ly = tid >> 5;        // local row 0..7
    const int x4 = xg * 4;
    const int y  = (int)(sub * 8u) + ly;

    const float step = 2.0f / 127.0f;
    const float gy  = (float)y  * step - 1.0f;
    const float gx0 = (float)x4 * step - 1.0f;

    // heatmap: exp(-50*r^2(kp_mean)) - exp(-50*r^2(kp_app)); exact 0 at d==0
    const float dy1 = gy - my, dy0 = gy - kay;
    const float dy1sq = dy1 * dy1, dy0sq = dy0 * dy0;
    float hv[4];
#pragma unroll
    for (int j = 0; j < 4; ++j) {
        const float gx = gx0 + (float)j * step;
        const float dx1 = gx - mx, dx0 = gx - kax;
        hv[j] = __expf(-50.0f * (dx1 * dx1 + dy1sq))
              - __expf(-50.0f * (dx0 * dx0 + dy0sq));
    }

    // deformed: uniform-weight blend of shifted rows from LDS
    float4 dvc[CC];
#pragma unroll
    for (int c = 0; c < CC; ++c) {
        const float* row0 = &P[c][ly][x4];
        const float* row1 = &P[c][ly + 1][x4];
        const float4 A = *(const float4*)row0;
        const float  ea = row0[4];
        const float4 B = *(const float4*)row1;
        const float  eb = row1[4];
        const float h0x = wx0 * A.x + wx1 * A.y;
        const float h0y = wx0 * A.y + wx1 * A.z;
        const float h0z = wx0 * A.z + wx1 * A.w;
        const float h0w = wx0 * A.w + wx1 * ea;
        const float h1x = wx0 * B.x + wx1 * B.y;
        const float h1y = wx0 * B.y + wx1 * B.z;
        const float h1z = wx0 * B.z + wx1 * B.w;
        const float h1w = wx0 * B.w + wx1 * eb;
        dvc[c] = make_float4(wy0 * h0x + wy1 * h1x,
                             wy0 * h0y + wy1 * h1y,
                             wy0 * h0z + wy1 * h1z,
                             wy0 * h0w + wy1 * h1w);
    }

    // ---- stores: out[b][k*6+c][d][y][x] ----
    const size_t chs  = (size_t)DD * HH * WW;  // 262144
    const size_t base = ((((size_t)b * (KK * 6) + k * 6) * DD + d) * HH + y) * WW + (size_t)x4;

    *(float4*)(out + base)         = make_float4(hv[0], hv[1], hv[2], hv[3]);
    *(float4*)(out + base + chs)   = make_float4(vdx, vdx, vdx, vdx);
    *(float4*)(out + base + 2*chs) = make_float4(vdy, vdy, vdy, vdy);
#pragma unroll
    for (int c = 0; c < CC; ++c)
        *(float4*)(out + base + (size_t)(3 + c) * chs) = dvc[c];
}

extern "C" void kernel_launch(void* const* d_in, const int* in_sizes, int n_in,
                              void* d_out, int out_size, void* d_ws, size_t ws_size,
                              hipStream_t stream) {
    const float* kp_app = (const float*)d_in[0];   // (4,1,10,2)
    const float* kp_vid = (const float*)d_in[1];   // (4,16,10,2)
    const float* img    = (const float*)d_in[2];   // (4,3,1,128,128)
    float* out = (float*)d_out;                    // (4,60,16,128,128)

    const int nblocks = BS * DD * KK * 16;         // 10240
    movement_embed_kernel<<<nblocks, 256, 0, stream>>>(kp_app, kp_vid, img, out);
}